// Round 1
// baseline (3131.974 us; speedup 1.0000x reference)
//
#include <hip/hip_runtime.h>
#include <math.h>

typedef __attribute__((ext_vector_type(8))) short short8;
typedef __attribute__((ext_vector_type(4))) float f32x4;

#define B_ 2
#define S_ 2048
#define D_ 1024
#define H_ 8
#define DH_ 128
#define NA_ 128
#define V_ 32000
#define MASKID_ 31999
#define Q_ 2048
#define KV_ 4096
#define KVP_ 4128
#define NROWS_ 4096
#define NSL_ 16
#define SLW_ 2000

__device__ __forceinline__ float bf2f(ushort u){ union{uint u;float f;}v; v.u=(uint)u<<16; return v.f; }
__device__ __forceinline__ ushort f2bf(float f){ union{float f;uint u;}v; v.f=f; return (ushort)((v.u + 0x7fffu + ((v.u>>16)&1u))>>16); }

__device__ __forceinline__ f32x4 mfma16(short8 a, short8 b, f32x4 c){
  return __builtin_amdgcn_mfma_f32_16x16x32_bf16(a,b,c,0,0,0);
}
__device__ __forceinline__ float rmax16(float v){
  #pragma unroll
  for(int m=1;m<16;m<<=1) v = fmaxf(v, __shfl_xor(v,m));
  return v;
}
__device__ __forceinline__ float rsum16(float v){
  #pragma unroll
  for(int m=1;m<16;m<<=1) v += __shfl_xor(v,m);
  return v;
}

// ---------------- meta: draft ids / labels / positions ----------------
__global__ void k_meta(const int* __restrict__ ids, const int* __restrict__ anch,
                       int* __restrict__ draft, int* __restrict__ labels, int* __restrict__ posf){
  int idx = blockIdx.x*256 + threadIdx.x;
  if (idx >= NROWS_) return;
  int b = idx >> 11, i = idx & (Q_-1);
  int p = i & 15;
  int a = anch[b*NA_ + (i>>4)];
  int pos = a + p;
  posf[idx] = pos;
  int gi = pos < S_ ? pos : S_-1;
  int tok = ids[b*S_ + gi];
  bool isa = (p==0);
  draft[idx] = isa ? tok : MASKID_;
  labels[idx] = (!isa && pos < S_) ? tok : -100;
}

// ---------------- f32 -> bf16 convert ----------------
__global__ void k_cvt(const float* __restrict__ src, ushort* __restrict__ dst, int n8){
  int i = blockIdx.x*256 + threadIdx.x;
  if (i >= n8) return;
  const float4* s = (const float4*)(src + (size_t)i*8);
  float4 a = s[0], b = s[1];
  short8 u;
  u[0]=(short)f2bf(a.x); u[1]=(short)f2bf(a.y); u[2]=(short)f2bf(a.z); u[3]=(short)f2bf(a.w);
  u[4]=(short)f2bf(b.x); u[5]=(short)f2bf(b.y); u[6]=(short)f2bf(b.z); u[7]=(short)f2bf(b.w);
  *(short8*)(dst + (size_t)i*8) = u;
}

// ---------------- hidden (L,B,S,D) -> hcat (B,S,L*D) bf16 ----------------
__global__ void k_hcat(const float* __restrict__ hs, ushort* __restrict__ hc){
  int idx = blockIdx.x*256 + threadIdx.x;
  if (idx >= NROWS_*384) return;
  int f8 = idx % 384; int row = idx / 384;
  int b = row >> 11, s = row & (S_-1);
  int f0 = f8*8, l = f0 >> 10, d = f0 & 1023;
  const float4* s4 = (const float4*)(hs + ((((size_t)l*B_ + b)*S_ + s)*D_ + d));
  float4 a = s4[0], c = s4[1];
  short8 u;
  u[0]=(short)f2bf(a.x); u[1]=(short)f2bf(a.y); u[2]=(short)f2bf(a.z); u[3]=(short)f2bf(a.w);
  u[4]=(short)f2bf(c.x); u[5]=(short)f2bf(c.y); u[6]=(short)f2bf(c.z); u[7]=(short)f2bf(c.w);
  *(short8*)(hc + (size_t)row*3072 + f0) = u;
}

// ---------------- embedding gather -> bf16 ----------------
__global__ void k_gather(const float* __restrict__ et, const int* __restrict__ draft, ushort* __restrict__ emb){
  int idx = blockIdx.x*256 + threadIdx.x;
  int row = idx >> 7, c = (idx & 127)*8;
  int id = draft[row];
  const float4* s4 = (const float4*)(et + (size_t)id*D_ + c);
  float4 a = s4[0], b = s4[1];
  short8 u;
  u[0]=(short)f2bf(a.x); u[1]=(short)f2bf(a.y); u[2]=(short)f2bf(a.z); u[3]=(short)f2bf(a.w);
  u[4]=(short)f2bf(b.x); u[5]=(short)f2bf(b.y); u[6]=(short)f2bf(b.z); u[7]=(short)f2bf(b.w);
  *(short8*)(emb + (size_t)row*D_ + c) = u;
}

// ---------------- generic GEMM: C(MxN) = A(MxK) * B(NxK)^T, bf16 in ----------------
// 128x128 tile, 4 waves (2x2), 4x4 16x16 frags per wave, global_load_lds staging
// with k-group swizzle applied on the GLOBAL source (linear LDS dest, swizzled read).
template<int OBF>
__global__ __launch_bounds__(256) void k_gemm(const ushort* __restrict__ A, const ushort* __restrict__ Bm,
                       void* __restrict__ C, int N, int K){
  __shared__ ushort lA[128*32];
  __shared__ ushort lB[128*32];
  const int lane = threadIdx.x & 63, w = threadIdx.x >> 6;
  const int l15 = lane & 15, g = lane >> 4;
  const int bm = blockIdx.x, bn = blockIdx.y;
  const int wm = w >> 1, wn = w & 1;
  f32x4 acc[4][4];
  #pragma unroll
  for (int a0=0;a0<4;++a0)
    #pragma unroll
    for (int a1=0;a1<4;++a1) acc[a0][a1] = f32x4{0.f,0.f,0.f,0.f};
  int rowS[2], kgS[2];
  #pragma unroll
  for (int i=0;i<2;++i){
    int o = w*1024 + i*4096 + lane*16;
    rowS[i] = o >> 6;
    kgS[i] = (((o>>4)&3) - (rowS[i]>>1)) & 3;
  }
  for (int k0 = 0; k0 < K; k0 += 32){
    #pragma unroll
    for (int i=0;i<2;++i){
      const ushort* sa = A + (size_t)(bm*128 + rowS[i])*K + k0 + kgS[i]*8;
      const ushort* sb = Bm + (size_t)(bn*128 + rowS[i])*K + k0 + kgS[i]*8;
      __builtin_amdgcn_global_load_lds((const __attribute__((address_space(1))) void*)sa,
          (__attribute__((address_space(3))) void*)((char*)lA + w*1024 + i*4096), 16, 0, 0);
      __builtin_amdgcn_global_load_lds((const __attribute__((address_space(1))) void*)sb,
          (__attribute__((address_space(3))) void*)((char*)lB + w*1024 + i*4096), 16, 0, 0);
    }
    __syncthreads();
    short8 af[4], bf[4];
    #pragma unroll
    for (int mf=0;mf<4;++mf){
      int rr = wm*64 + mf*16 + l15;
      af[mf] = *(const short8*)((const char*)lA + rr*64 + (((g + (rr>>1))&3)*16));
    }
    #pragma unroll
    for (int nf=0;nf<4;++nf){
      int rr = wn*64 + nf*16 + l15;
      bf[nf] = *(const short8*)((const char*)lB + rr*64 + (((g + (rr>>1))&3)*16));
    }
    #pragma unroll
    for (int mf=0;mf<4;++mf)
      #pragma unroll
      for (int nf=0;nf<4;++nf)
        acc[mf][nf] = mfma16(af[mf], bf[nf], acc[mf][nf]);
    __syncthreads();
  }
  #pragma unroll
  for (int mf=0;mf<4;++mf)
  #pragma unroll
  for (int nf=0;nf<4;++nf){
    int row0 = bm*128 + wm*64 + mf*16 + g*4;
    int col  = bn*128 + wn*64 + nf*16 + l15;
    #pragma unroll
    for (int r=0;r<4;++r){
      if (OBF) ((ushort*)C)[(size_t)(row0+r)*N + col] = f2bf(acc[mf][nf][r]);
      else     ((float*)C)[(size_t)(row0+r)*N + col] = acc[mf][nf][r];
    }
  }
}

// ---------------- RoPE + scatter: draft side (q, kd, vd) ----------------
__global__ void k_rope_draft(const ushort* __restrict__ C1, const int* __restrict__ posf,
    ushort* __restrict__ qb, ushort* __restrict__ kb, ushort* __restrict__ vT){
  int idx = blockIdx.x*256 + threadIdx.x; // B*Q*H*64
  int d2 = idx & 63, h = (idx>>6)&7, i = (idx>>9)&(Q_-1), b = idx>>20;
  int row = b*Q_ + i;
  int pos = posf[row];
  float inv = __expf(-(float)d2 * 0.14391156831212787f); // ln(10000)/64
  float ang = (float)pos * inv;
  float sn, cs; sincosf(ang, &sn, &cs);
  const ushort* cr = C1 + (size_t)row*3072 + h*DH_ + d2;
  float x1 = bf2f(cr[0]), x2 = bf2f(cr[64]);
  size_t qo = (size_t)row*D_ + h*DH_ + d2;
  qb[qo] = f2bf(x1*cs - x2*sn); qb[qo+64] = f2bf(x1*sn + x2*cs);
  x1 = bf2f(cr[1024]); x2 = bf2f(cr[1088]);
  size_t ko = ((size_t)(b*KV_ + S_ + i))*D_ + h*DH_ + d2;
  kb[ko] = f2bf(x1*cs - x2*sn); kb[ko+64] = f2bf(x1*sn + x2*cs);
  x1 = bf2f(cr[2048]); x2 = bf2f(cr[2112]);
  size_t vo = ((size_t)((b*H_ + h)*DH_ + d2))*KVP_ + (S_ + i);
  vT[vo] = f2bf(x1); vT[vo + (size_t)64*KVP_] = f2bf(x2);
}

// ---------------- RoPE + scatter: ctx side (kc, vc) ----------------
__global__ void k_rope_ctx(const ushort* __restrict__ C2,
    ushort* __restrict__ kb, ushort* __restrict__ vT){
  int idx = blockIdx.x*256 + threadIdx.x; // B*S*H*64
  int d2 = idx & 63, h = (idx>>6)&7, i = (idx>>9)&(S_-1), b = idx>>20;
  int row = b*S_ + i;
  float inv = __expf(-(float)d2 * 0.14391156831212787f);
  float ang = (float)i * inv;
  float sn, cs; sincosf(ang, &sn, &cs);
  const ushort* cr = C2 + (size_t)row*2048 + h*DH_ + d2;
  float x1 = bf2f(cr[0]), x2 = bf2f(cr[64]);
  size_t ko = ((size_t)(b*KV_ + i))*D_ + h*DH_ + d2;
  kb[ko] = f2bf(x1*cs - x2*sn); kb[ko+64] = f2bf(x1*sn + x2*cs);
  x1 = bf2f(cr[1024]); x2 = bf2f(cr[1088]);
  size_t vo = ((size_t)((b*H_ + h)*DH_ + d2))*KVP_ + i;
  vT[vo] = f2bf(x1); vT[vo + (size_t)64*KVP_] = f2bf(x2);
}

// ---------------- block-sparse flash attention ----------------
// one wave per (b, q-block of 16, h); K fed as B-frags direct from global,
// V pre-transposed (vT) so PV B-frags are contiguous; P via padded-LDS roundtrip.
__global__ __launch_bounds__(256) void k_attn(const ushort* __restrict__ qb, const ushort* __restrict__ kb,
    const ushort* __restrict__ vT, const int* __restrict__ anch, ushort* __restrict__ ao){
  __shared__ float pbuf[4][16*36];
  const int lane = threadIdx.x & 63, w = threadIdx.x >> 6;
  const int l15 = lane & 15, g = lane >> 4;
  const int wi = blockIdx.x*4 + w;
  const int b = wi >> 10, qblk = (wi >> 3) & (NA_-1), h = wi & 7;
  const int anc = anch[b*NA_ + qblk];
  float* pb = pbuf[w];
  short8 aq[4];
  {
    const ushort* qr = qb + ((size_t)(b*Q_ + qblk*16 + l15))*D_ + h*DH_ + g*8;
    #pragma unroll
    for (int kc=0;kc<4;++kc) aq[kc] = *(const short8*)(qr + kc*32);
  }
  f32x4 o[8];
  #pragma unroll
  for (int cc=0;cc<8;++cc) o[cc] = f32x4{0.f,0.f,0.f,0.f};
  float m[4] = {-1e30f,-1e30f,-1e30f,-1e30f};
  float sl[4] = {0.f,0.f,0.f,0.f};
  const float SC = 0.08838834764831845f; // 1/sqrt(128)
  const ushort* vbase = vT + ((size_t)((b*H_ + h)*DH_))*KVP_;

  auto process = [&](int kv0, int limit){
    const bool have2 = (limit - kv0) > 16;
    f32x4 sc0 = {0.f,0.f,0.f,0.f}, sc1 = {0.f,0.f,0.f,0.f};
    const ushort* kr = kb + ((size_t)(b*KV_ + kv0 + l15))*D_ + h*DH_ + g*8;
    #pragma unroll
    for (int kc=0;kc<4;++kc){
      short8 bk = *(const short8*)(kr + kc*32);
      sc0 = mfma16(aq[kc], bk, sc0);
    }
    if (have2){
      const ushort* kr2 = kr + (size_t)16*D_;
      #pragma unroll
      for (int kc=0;kc<4;++kc){
        short8 bk = *(const short8*)(kr2 + kc*32);
        sc1 = mfma16(aq[kc], bk, sc1);
      }
    }
    int key0 = kv0 + l15, key1 = kv0 + 16 + l15;
    #pragma unroll
    for (int r=0;r<4;++r){
      float s0 = (key0 < limit) ? sc0[r]*SC : -1e30f;
      float s1 = (have2 && key1 < limit) ? sc1[r]*SC : -1e30f;
      float cm = rmax16(fmaxf(s0, s1));
      float mn = fmaxf(m[r], cm);
      float esc = __expf(m[r] - mn);
      float p0 = __expf(s0 - mn), p1 = __expf(s1 - mn);
      float rs = rsum16(p0 + p1);
      sl[r] = sl[r]*esc + rs;
      m[r] = mn;
      #pragma unroll
      for (int cc=0;cc<8;++cc) o[cc][r] *= esc;
      int q = g*4 + r;
      pb[q*36 + l15] = p0;
      pb[q*36 + 16 + l15] = p1;
    }
    asm volatile("s_waitcnt lgkmcnt(0)" ::: "memory");
    __builtin_amdgcn_sched_barrier(0);
    const float* pr = pb + l15*36 + g*8;
    float4 pa0 = *(const float4*)pr;
    float4 pa1 = *(const float4*)(pr + 4);
    short8 pa;
    pa[0]=(short)f2bf(pa0.x); pa[1]=(short)f2bf(pa0.y); pa[2]=(short)f2bf(pa0.z); pa[3]=(short)f2bf(pa0.w);
    pa[4]=(short)f2bf(pa1.x); pa[5]=(short)f2bf(pa1.y); pa[6]=(short)f2bf(pa1.z); pa[7]=(short)f2bf(pa1.w);
    const ushort* vr = vbase + kv0 + g*8;
    #pragma unroll
    for (int cc=0;cc<8;++cc){
      short8 bv = *(const short8*)(vr + (size_t)(cc*16 + l15)*KVP_);
      o[cc] = mfma16(pa, bv, o[cc]);
    }
  };
  for (int kv0 = 0; kv0 < anc; kv0 += 32) process(kv0, anc);
  {
    int kv0 = S_ + qblk*16;
    process(kv0, kv0 + 16);
  }
  #pragma unroll
  for (int cc=0;cc<8;++cc){
    #pragma unroll
    for (int r=0;r<4;++r){
      float val = o[cc][r] / sl[r];
      int q = g*4 + r;
      ao[((size_t)(b*Q_ + qblk*16 + q))*D_ + h*DH_ + cc*16 + l15] = f2bf(val);
    }
  }
}

// ---------------- residual + RMSNorm -> h bf16 ----------------
__global__ __launch_bounds__(256) void k_rms(const float* __restrict__ wo_out, const float* __restrict__ et,
    const int* __restrict__ draft, const float* __restrict__ nw, ushort* __restrict__ hb){
  const int row = blockIdx.x, tid = threadIdx.x;
  const int lane = tid & 63, w = tid >> 6;
  const float* wr = wo_out + (size_t)row*D_;
  const float* er = et + (size_t)draft[row]*D_;
  float v[4]; float ss = 0.f;
  #pragma unroll
  for (int j=0;j<4;++j){
    int d = tid + j*256;
    v[j] = er[d] + wr[d];
    ss += v[j]*v[j];
  }
  #pragma unroll
  for (int msk=1; msk<64; msk<<=1) ss += __shfl_xor(ss, msk);
  __shared__ float red[4];
  if (lane == 0) red[w] = ss;
  __syncthreads();
  float tot = red[0]+red[1]+red[2]+red[3];
  float rs = rsqrtf(tot*(1.f/1024.f) + 1e-6f);
  #pragma unroll
  for (int j=0;j<4;++j){
    int d = tid + j*256;
    hb[(size_t)row*D_ + d] = f2bf(v[j]*rs*nw[d]);
  }
}

// ---------------- fused lm_head: logits tile + online (max, lse, argmax, label) ----------------
__global__ __launch_bounds__(512) void k_lmhead(const ushort* __restrict__ hb, const ushort* __restrict__ wv,
    const int* __restrict__ labels, float* __restrict__ pm, float* __restrict__ pl,
    float* __restrict__ pbv, int* __restrict__ pbi, float* __restrict__ plb){
  const int lane = threadIdx.x & 63, w = threadIdx.x >> 6;
  const int l15 = lane & 15, g = lane >> 4;
  const int rg = blockIdx.x, slc = blockIdx.y;
  const int r0 = rg*128 + w*16;
  short8 a[32];
  {
    const ushort* ar = hb + (size_t)(r0 + l15)*D_ + g*8;
    #pragma unroll
    for (int kc=0;kc<32;++kc) a[kc] = *(const short8*)(ar + kc*32);
  }
  int lbl[4];
  #pragma unroll
  for (int r=0;r<4;++r) lbl[r] = labels[r0 + g*4 + r];
  float m[4] = {-1e30f,-1e30f,-1e30f,-1e30f};
  float ll[4] = {0.f,0.f,0.f,0.f};
  float bv[4] = {-1e30f,-1e30f,-1e30f,-1e30f};
  int   bi[4] = {0,0,0,0};
  float lb[4] = {-1e30f,-1e30f,-1e30f,-1e30f};
  const int col0 = slc*SLW_;
  for (int t=0;t<SLW_/16;++t){
    const int cb = col0 + t*16;
    f32x4 acc = {0.f,0.f,0.f,0.f};
    const ushort* wr = wv + (size_t)(cb + l15)*D_ + g*8;
    #pragma unroll
    for (int kc=0;kc<32;++kc){
      short8 bw = *(const short8*)(wr + kc*32);
      acc = mfma16(a[kc], bw, acc);
    }
    const int col = cb + l15;
    #pragma unroll
    for (int r=0;r<4;++r){
      float s = acc[r];
      float tm = rmax16(s);
      float mn = fmaxf(m[r], tm);
      ll[r] = ll[r]*__expf(m[r]-mn) + rsum16(__expf(s - mn));
      m[r] = mn;
      float vv = s; int ci = col;
      #pragma unroll
      for (int msk=1; msk<16; msk<<=1){
        float ov = __shfl_xor(vv, msk);
        int oi = __shfl_xor(ci, msk);
        if (ov > vv || (ov == vv && oi < ci)){ vv = ov; ci = oi; }
      }
      if (vv > bv[r] || (vv == bv[r] && ci < bi[r])){ bv[r] = vv; bi[r] = ci; }
      float lv = (col == lbl[r]) ? s : -1e30f;
      lb[r] = fmaxf(lb[r], rmax16(lv));
    }
  }
  if (l15 == 0){
    #pragma unroll
    for (int r=0;r<4;++r){
      int row = r0 + g*4 + r;
      size_t idx = (size_t)row*NSL_ + slc;
      pm[idx] = m[r]; pl[idx] = ll[r]; pbv[idx] = bv[r]; pbi[idx] = bi[r]; plb[idx] = lb[r];
    }
  }
}

// ---------------- combine vocab slices -> per-block loss sums (deterministic) ----------------
__global__ __launch_bounds__(256) void k_combine(const float* __restrict__ pm, const float* __restrict__ pl,
    const float* __restrict__ pbv, const int* __restrict__ pbi, const float* __restrict__ plb,
    const int* __restrict__ labels, float* __restrict__ pblk){
  const int row = blockIdx.x*256 + threadIdx.x;
  float M = -1e30f;
  for (int s=0;s<NSL_;++s) M = fmaxf(M, pm[(size_t)row*NSL_+s]);
  float Lx = 0.f;
  for (int s=0;s<NSL_;++s) Lx += pl[(size_t)row*NSL_+s]*__expf(pm[(size_t)row*NSL_+s]-M);
  float logZ = M + logf(Lx);
  float bv = -1e30f; int bi = 0; float lb = -1e30f;
  for (int s=0;s<NSL_;++s){
    float v = pbv[(size_t)row*NSL_+s];
    if (v > bv){ bv = v; bi = pbi[(size_t)row*NSL_+s]; }
    lb = fmaxf(lb, plb[(size_t)row*NSL_+s]);
  }
  int lab = labels[row];
  bool valid = lab != -100;
  int p = row & 15;
  float wgt = (valid && p > 0) ? __expf(-(float)(p-1)*(1.f/7.f)) : 0.f;
  float nll = logZ - lb;
  float t0 = wgt*nll, t1 = wgt;
  float t2 = (valid && bi == lab) ? 1.f : 0.f, t3 = valid ? 1.f : 0.f;
  #pragma unroll
  for (int msk=1; msk<64; msk<<=1){
    t0 += __shfl_xor(t0, msk); t1 += __shfl_xor(t1, msk);
    t2 += __shfl_xor(t2, msk); t3 += __shfl_xor(t3, msk);
  }
  __shared__ float red[4][4];
  const int lane = threadIdx.x & 63, w = threadIdx.x >> 6;
  if (lane == 0){ red[w][0]=t0; red[w][1]=t1; red[w][2]=t2; red[w][3]=t3; }
  __syncthreads();
  if (threadIdx.x == 0){
    float s0=0,s1=0,s2=0,s3=0;
    for (int i=0;i<4;++i){ s0+=red[i][0]; s1+=red[i][1]; s2+=red[i][2]; s3+=red[i][3]; }
    pblk[blockIdx.x*4+0]=s0; pblk[blockIdx.x*4+1]=s1; pblk[blockIdx.x*4+2]=s2; pblk[blockIdx.x*4+3]=s3;
  }
}

__global__ void k_final(const float* __restrict__ pblk, float* __restrict__ out){
  if (threadIdx.x != 0 || blockIdx.x != 0) return;
  float s0=0,s1=0,s2=0,s3=0;
  for (int i=0;i<16;++i){ s0+=pblk[i*4]; s1+=pblk[i*4+1]; s2+=pblk[i*4+2]; s3+=pblk[i*4+3]; }
  out[0] = s0 / fmaxf(s1, 1e-6f);
  out[1] = s2 / fmaxf(s3, 1.f);
}

extern "C" void kernel_launch(void* const* d_in, const int* in_sizes, int n_in,
                              void* d_out, int out_size, void* d_ws, size_t ws_size,
                              hipStream_t stream){
  const int*   ids  = (const int*)d_in[0];
  const float* hs   = (const float*)d_in[1];
  const int*   anch = (const int*)d_in[2];
  const float* lmw  = (const float*)d_in[3];
  const float* nw   = (const float*)d_in[4];
  const float* fcw  = (const float*)d_in[5];
  const float* et   = (const float*)d_in[6];
  const float* wq   = (const float*)d_in[7];
  const float* wk   = (const float*)d_in[8];
  const float* wvp  = (const float*)d_in[9];
  const float* wo   = (const float*)d_in[10];
  float* out = (float*)d_out;
  (void)in_sizes; (void)n_in; (void)out_size; (void)ws_size;

  char* ws = (char*)d_ws;
  size_t off = 0;
  auto alloc = [&](size_t bytes)->char*{ char* p = ws + off; off = (off + bytes + 255) & ~(size_t)255; return p; };
  ushort* fcW   = (ushort*)alloc((size_t)1024*3072*2);
  ushort* Wqkv  = (ushort*)alloc((size_t)3072*1024*2);
  ushort* woW   = (ushort*)alloc((size_t)1024*1024*2);
  ushort* lmW   = (ushort*)alloc((size_t)V_*1024*2);
  ushort* ctx   = (ushort*)alloc((size_t)4096*1024*2);
  ushort* emb   = (ushort*)alloc((size_t)4096*1024*2);
  ushort* hcat  = (ushort*)alloc((size_t)4096*3072*2);   // reused as C1 after ctx GEMM
  ushort* C1 = hcat;
  ushort* C2    = (ushort*)alloc((size_t)4096*2048*2);   // reused as wo_out (f32, same bytes)
  float* wo_out = (float*)C2;
  ushort* qbuf  = (ushort*)alloc((size_t)4096*1024*2);
  ushort* kbuf  = (ushort*)alloc((size_t)B_*KV_*1024*2);
  ushort* vT    = (ushort*)alloc((size_t)B_*H_*DH_*KVP_*2);
  ushort* ao    = (ushort*)alloc((size_t)4096*1024*2);
  ushort* hb    = (ushort*)alloc((size_t)4096*1024*2);
  int* draft  = (int*)alloc(4096*4);
  int* labels = (int*)alloc(4096*4);
  int* posf   = (int*)alloc(4096*4);
  float* pm   = (float*)alloc((size_t)4096*NSL_*4);
  float* pl   = (float*)alloc((size_t)4096*NSL_*4);
  float* pbv  = (float*)alloc((size_t)4096*NSL_*4);
  int*   pbi  = (int*)alloc((size_t)4096*NSL_*4);
  float* plb  = (float*)alloc((size_t)4096*NSL_*4);
  float* pblk = (float*)alloc(16*4*4);

  k_meta<<<16,256,0,stream>>>(ids, anch, draft, labels, posf);
  k_hcat<<<6144,256,0,stream>>>(hs, hcat);
  k_cvt<<<1536,256,0,stream>>>(fcw, fcW, 1024*3072/8);
  k_cvt<<<512,256,0,stream>>>(wq, Wqkv, 1024*1024/8);
  k_cvt<<<512,256,0,stream>>>(wk, Wqkv + (size_t)1024*1024, 1024*1024/8);
  k_cvt<<<512,256,0,stream>>>(wvp, Wqkv + (size_t)2048*1024, 1024*1024/8);
  k_cvt<<<512,256,0,stream>>>(wo, woW, 1024*1024/8);
  k_cvt<<<16000,256,0,stream>>>(lmw, lmW, V_*1024/8);
  k_gather<<<2048,256,0,stream>>>(et, draft, emb);
  k_gemm<1><<<dim3(32,8),256,0,stream>>>(hcat, fcW, ctx, 1024, 3072);
  k_gemm<1><<<dim3(32,24),256,0,stream>>>(emb, Wqkv, C1, 3072, 1024);
  k_gemm<1><<<dim3(32,16),256,0,stream>>>(ctx, Wqkv + (size_t)1024*1024, C2, 2048, 1024);
  k_rope_draft<<<8192,256,0,stream>>>(C1, posf, qbuf, kbuf, vT);
  k_rope_ctx<<<8192,256,0,stream>>>(C2, kbuf, vT);
  k_attn<<<512,256,0,stream>>>(qbuf, kbuf, vT, anch, ao);
  k_gemm<0><<<dim3(32,8),256,0,stream>>>(ao, woW, wo_out, 1024, 1024);
  k_rms<<<4096,256,0,stream>>>(wo_out, et, draft, nw, hb);
  k_lmhead<<<dim3(32,16),512,0,stream>>>(hb, lmW, labels, pm, pl, pbv, pbi, plb);
  k_combine<<<16,256,0,stream>>>(pm, pl, pbv, pbi, plb, labels, pblk);
  k_final<<<1,64,0,stream>>>(pblk, out);
}

// Round 2
// 1012.784 us; speedup vs baseline: 3.0924x; 3.0924x over previous
//
#include <hip/hip_runtime.h>
#include <math.h>

typedef __attribute__((ext_vector_type(8))) short short8;
typedef __attribute__((ext_vector_type(4))) float f32x4;

#define B_ 2
#define S_ 2048
#define D_ 1024
#define H_ 8
#define DH_ 128
#define NA_ 128
#define V_ 32000
#define MASKID_ 31999
#define Q_ 2048
#define KV_ 4096
#define KVP_ 4128
#define NROWS_ 4096
#define NP_ 500

__device__ __forceinline__ float bf2f(ushort u){ union{uint u;float f;}v; v.u=(uint)u<<16; return v.f; }
__device__ __forceinline__ ushort f2bf(float f){ union{float f;uint u;}v; v.f=f; return (ushort)((v.u + 0x7fffu + ((v.u>>16)&1u))>>16); }

__device__ __forceinline__ f32x4 mfma16(short8 a, short8 b, f32x4 c){
  return __builtin_amdgcn_mfma_f32_16x16x32_bf16(a,b,c,0,0,0);
}
__device__ __forceinline__ float rmax16(float v){
  #pragma unroll
  for(int m=1;m<16;m<<=1) v = fmaxf(v, __shfl_xor(v,m));
  return v;
}
__device__ __forceinline__ float rsum16(float v){
  #pragma unroll
  for(int m=1;m<16;m<<=1) v += __shfl_xor(v,m);
  return v;
}

// ---------------- meta: draft ids / labels / positions ----------------
__global__ void k_meta(const int* __restrict__ ids, const int* __restrict__ anch,
                       int* __restrict__ draft, int* __restrict__ labels, int* __restrict__ posf){
  int idx = blockIdx.x*256 + threadIdx.x;
  if (idx >= NROWS_) return;
  int b = idx >> 11, i = idx & (Q_-1);
  int p = i & 15;
  int a = anch[b*NA_ + (i>>4)];
  int pos = a + p;
  posf[idx] = pos;
  int gi = pos < S_ ? pos : S_-1;
  int tok = ids[b*S_ + gi];
  bool isa = (p==0);
  draft[idx] = isa ? tok : MASKID_;
  labels[idx] = (!isa && pos < S_) ? tok : -100;
}

// ---------------- f32 -> bf16 convert ----------------
__global__ void k_cvt(const float* __restrict__ src, ushort* __restrict__ dst, int n8){
  int i = blockIdx.x*256 + threadIdx.x;
  if (i >= n8) return;
  const float4* s = (const float4*)(src + (size_t)i*8);
  float4 a = s[0], b = s[1];
  short8 u;
  u[0]=(short)f2bf(a.x); u[1]=(short)f2bf(a.y); u[2]=(short)f2bf(a.z); u[3]=(short)f2bf(a.w);
  u[4]=(short)f2bf(b.x); u[5]=(short)f2bf(b.y); u[6]=(short)f2bf(b.z); u[7]=(short)f2bf(b.w);
  *(short8*)(dst + (size_t)i*8) = u;
}

// ---------------- hidden (L,B,S,D) -> hcat (B,S,L*D) bf16 ----------------
__global__ void k_hcat(const float* __restrict__ hs, ushort* __restrict__ hc){
  int idx = blockIdx.x*256 + threadIdx.x;
  if (idx >= NROWS_*384) return;
  int f8 = idx % 384; int row = idx / 384;
  int b = row >> 11, s = row & (S_-1);
  int f0 = f8*8, l = f0 >> 10, d = f0 & 1023;
  const float4* s4 = (const float4*)(hs + ((((size_t)l*B_ + b)*S_ + s)*D_ + d));
  float4 a = s4[0], c = s4[1];
  short8 u;
  u[0]=(short)f2bf(a.x); u[1]=(short)f2bf(a.y); u[2]=(short)f2bf(a.z); u[3]=(short)f2bf(a.w);
  u[4]=(short)f2bf(c.x); u[5]=(short)f2bf(c.y); u[6]=(short)f2bf(c.z); u[7]=(short)f2bf(c.w);
  *(short8*)(hc + (size_t)row*3072 + f0) = u;
}

// ---------------- embedding gather -> bf16 ----------------
__global__ void k_gather(const float* __restrict__ et, const int* __restrict__ draft, ushort* __restrict__ emb){
  int idx = blockIdx.x*256 + threadIdx.x;
  int row = idx >> 7, c = (idx & 127)*8;
  int id = draft[row];
  const float4* s4 = (const float4*)(et + (size_t)id*D_ + c);
  float4 a = s4[0], b = s4[1];
  short8 u;
  u[0]=(short)f2bf(a.x); u[1]=(short)f2bf(a.y); u[2]=(short)f2bf(a.z); u[3]=(short)f2bf(a.w);
  u[4]=(short)f2bf(b.x); u[5]=(short)f2bf(b.y); u[6]=(short)f2bf(b.z); u[7]=(short)f2bf(b.w);
  *(short8*)(emb + (size_t)row*D_ + c) = u;
}

// ---------------- generic GEMM: C(MxN) = A(MxK) * B(NxK)^T, bf16 in ----------------
template<int OBF>
__global__ __launch_bounds__(256) void k_gemm(const ushort* __restrict__ A, const ushort* __restrict__ Bm,
                       void* __restrict__ C, int N, int K){
  __shared__ ushort lA[128*32];
  __shared__ ushort lB[128*32];
  const int lane = threadIdx.x & 63, w = threadIdx.x >> 6;
  const int l15 = lane & 15, g = lane >> 4;
  const int bm = blockIdx.x, bn = blockIdx.y;
  const int wm = w >> 1, wn = w & 1;
  f32x4 acc[4][4];
  #pragma unroll
  for (int a0=0;a0<4;++a0)
    #pragma unroll
    for (int a1=0;a1<4;++a1) acc[a0][a1] = f32x4{0.f,0.f,0.f,0.f};
  int rowS[2], kgS[2];
  #pragma unroll
  for (int i=0;i<2;++i){
    int o = w*1024 + i*4096 + lane*16;
    rowS[i] = o >> 6;
    kgS[i] = (((o>>4)&3) - (rowS[i]>>1)) & 3;
  }
  for (int k0 = 0; k0 < K; k0 += 32){
    #pragma unroll
    for (int i=0;i<2;++i){
      const ushort* sa = A + (size_t)(bm*128 + rowS[i])*K + k0 + kgS[i]*8;
      const ushort* sb = Bm + (size_t)(bn*128 + rowS[i])*K + k0 + kgS[i]*8;
      __builtin_amdgcn_global_load_lds((const __attribute__((address_space(1))) void*)sa,
          (__attribute__((address_space(3))) void*)((char*)lA + w*1024 + i*4096), 16, 0, 0);
      __builtin_amdgcn_global_load_lds((const __attribute__((address_space(1))) void*)sb,
          (__attribute__((address_space(3))) void*)((char*)lB + w*1024 + i*4096), 16, 0, 0);
    }
    __syncthreads();
    short8 af[4], bf[4];
    #pragma unroll
    for (int mf=0;mf<4;++mf){
      int rr = wm*64 + mf*16 + l15;
      af[mf] = *(const short8*)((const char*)lA + rr*64 + (((g + (rr>>1))&3)*16));
    }
    #pragma unroll
    for (int nf=0;nf<4;++nf){
      int rr = wn*64 + nf*16 + l15;
      bf[nf] = *(const short8*)((const char*)lB + rr*64 + (((g + (rr>>1))&3)*16));
    }
    #pragma unroll
    for (int mf=0;mf<4;++mf)
      #pragma unroll
      for (int nf=0;nf<4;++nf)
        acc[mf][nf] = mfma16(af[mf], bf[nf], acc[mf][nf]);
    __syncthreads();
  }
  #pragma unroll
  for (int mf=0;mf<4;++mf)
  #pragma unroll
  for (int nf=0;nf<4;++nf){
    int row0 = bm*128 + wm*64 + mf*16 + g*4;
    int col  = bn*128 + wn*64 + nf*16 + l15;
    #pragma unroll
    for (int r=0;r<4;++r){
      if (OBF) ((ushort*)C)[(size_t)(row0+r)*N + col] = f2bf(acc[mf][nf][r]);
      else     ((float*)C)[(size_t)(row0+r)*N + col] = acc[mf][nf][r];
    }
  }
}

// ---------------- lm_head GEMM with fused softmax/argmax epilogue ----------------
// C tile 128x128 over (rows=4096, vocab=32000), K=1024. Per-wave epilogue reduces
// its 64 columns per row; partials written [slice][row], slice = bn*2+wn (NP_=500).
__global__ __launch_bounds__(256) void k_lmgemm(const ushort* __restrict__ A, const ushort* __restrict__ Bm,
    float* __restrict__ pm, float* __restrict__ pl, float* __restrict__ pbv, int* __restrict__ pbi){
  __shared__ ushort lA[128*32];
  __shared__ ushort lB[128*32];
  const int lane = threadIdx.x & 63, w = threadIdx.x >> 6;
  const int l15 = lane & 15, g = lane >> 4;
  const int bm = blockIdx.x, bn = blockIdx.y;
  const int wm = w >> 1, wn = w & 1;
  f32x4 acc[4][4];
  #pragma unroll
  for (int a0=0;a0<4;++a0)
    #pragma unroll
    for (int a1=0;a1<4;++a1) acc[a0][a1] = f32x4{0.f,0.f,0.f,0.f};
  int rowS[2], kgS[2];
  #pragma unroll
  for (int i=0;i<2;++i){
    int o = w*1024 + i*4096 + lane*16;
    rowS[i] = o >> 6;
    kgS[i] = (((o>>4)&3) - (rowS[i]>>1)) & 3;
  }
  for (int k0 = 0; k0 < 1024; k0 += 32){
    #pragma unroll
    for (int i=0;i<2;++i){
      const ushort* sa = A + (size_t)(bm*128 + rowS[i])*1024 + k0 + kgS[i]*8;
      const ushort* sb = Bm + (size_t)(bn*128 + rowS[i])*1024 + k0 + kgS[i]*8;
      __builtin_amdgcn_global_load_lds((const __attribute__((address_space(1))) void*)sa,
          (__attribute__((address_space(3))) void*)((char*)lA + w*1024 + i*4096), 16, 0, 0);
      __builtin_amdgcn_global_load_lds((const __attribute__((address_space(1))) void*)sb,
          (__attribute__((address_space(3))) void*)((char*)lB + w*1024 + i*4096), 16, 0, 0);
    }
    __syncthreads();
    short8 af[4], bfr[4];
    #pragma unroll
    for (int mf=0;mf<4;++mf){
      int rr = wm*64 + mf*16 + l15;
      af[mf] = *(const short8*)((const char*)lA + rr*64 + (((g + (rr>>1))&3)*16));
    }
    #pragma unroll
    for (int nf=0;nf<4;++nf){
      int rr = wn*64 + nf*16 + l15;
      bfr[nf] = *(const short8*)((const char*)lB + rr*64 + (((g + (rr>>1))&3)*16));
    }
    #pragma unroll
    for (int mf=0;mf<4;++mf)
      #pragma unroll
      for (int nf=0;nf<4;++nf)
        acc[mf][nf] = mfma16(af[mf], bfr[nf], acc[mf][nf]);
    __syncthreads();
  }
  // epilogue: per-row stats over this wave's 64 columns
  const int colb = bn*128 + wn*64 + l15;
  #pragma unroll
  for (int mf=0;mf<4;++mf){
    #pragma unroll
    for (int r=0;r<4;++r){
      float s0 = acc[mf][0][r], s1 = acc[mf][1][r], s2 = acc[mf][2][r], s3 = acc[mf][3][r];
      float M = rmax16(fmaxf(fmaxf(s0,s1), fmaxf(s2,s3)));
      float le = __expf(s0-M) + __expf(s1-M) + __expf(s2-M) + __expf(s3-M);
      float lsum = rsum16(le);
      float vv = s0; int ci = colb;
      if (s1 > vv){ vv=s1; ci=colb+16; }
      if (s2 > vv){ vv=s2; ci=colb+32; }
      if (s3 > vv){ vv=s3; ci=colb+48; }
      #pragma unroll
      for (int msk=1; msk<16; msk<<=1){
        float ov = __shfl_xor(vv, msk);
        int oi = __shfl_xor(ci, msk);
        if (ov > vv || (ov == vv && oi < ci)){ vv = ov; ci = oi; }
      }
      if (l15 == 0){
        int row = bm*128 + wm*64 + mf*16 + g*4 + r;
        size_t pidx = (size_t)(bn*2 + wn)*NROWS_ + row;
        pm[pidx] = M; pl[pidx] = lsum; pbv[pidx] = vv; pbi[pidx] = ci;
      }
    }
  }
}

// ---------------- label logit: plbl[row] = dot(hb[row], lmW[label]) ----------------
__global__ __launch_bounds__(256) void k_lbl(const ushort* __restrict__ hb, const ushort* __restrict__ wv,
    const int* __restrict__ labels, float* __restrict__ plbl){
  const int lane = threadIdx.x & 63, w = threadIdx.x >> 6;
  const int row = blockIdx.x*4 + w;
  int lab = labels[row];
  float s = 0.f;
  if (lab >= 0){
    const ushort* hr = hb + (size_t)row*1024 + lane*16;
    const ushort* wr = wv + (size_t)lab*1024 + lane*16;
    short8 h0 = *(const short8*)hr, h1 = *(const short8*)(hr+8);
    short8 w0 = *(const short8*)wr, w1 = *(const short8*)(wr+8);
    #pragma unroll
    for (int j=0;j<8;++j) s += bf2f((ushort)h0[j])*bf2f((ushort)w0[j]) + bf2f((ushort)h1[j])*bf2f((ushort)w1[j]);
  }
  #pragma unroll
  for (int msk=1; msk<64; msk<<=1) s += __shfl_xor(s, msk);
  if (lane == 0) plbl[row] = s;
}

// ---------------- RoPE + scatter: draft side (q, kd, vd) ----------------
__global__ void k_rope_draft(const ushort* __restrict__ C1, const int* __restrict__ posf,
    ushort* __restrict__ qb, ushort* __restrict__ kb, ushort* __restrict__ vT){
  int idx = blockIdx.x*256 + threadIdx.x; // B*Q*H*64
  int d2 = idx & 63, h = (idx>>6)&7, i = (idx>>9)&(Q_-1), b = idx>>20;
  int row = b*Q_ + i;
  int pos = posf[row];
  float inv = __expf(-(float)d2 * 0.14391156831212787f); // ln(10000)/64
  float ang = (float)pos * inv;
  float sn, cs; sincosf(ang, &sn, &cs);
  const ushort* cr = C1 + (size_t)row*3072 + h*DH_ + d2;
  float x1 = bf2f(cr[0]), x2 = bf2f(cr[64]);
  size_t qo = (size_t)row*D_ + h*DH_ + d2;
  qb[qo] = f2bf(x1*cs - x2*sn); qb[qo+64] = f2bf(x1*sn + x2*cs);
  x1 = bf2f(cr[1024]); x2 = bf2f(cr[1088]);
  size_t ko = ((size_t)(b*KV_ + S_ + i))*D_ + h*DH_ + d2;
  kb[ko] = f2bf(x1*cs - x2*sn); kb[ko+64] = f2bf(x1*sn + x2*cs);
  x1 = bf2f(cr[2048]); x2 = bf2f(cr[2112]);
  size_t vo = ((size_t)((b*H_ + h)*DH_ + d2))*KVP_ + (S_ + i);
  vT[vo] = f2bf(x1); vT[vo + (size_t)64*KVP_] = f2bf(x2);
}

// ---------------- RoPE + scatter: ctx side (kc, vc) ----------------
__global__ void k_rope_ctx(const ushort* __restrict__ C2,
    ushort* __restrict__ kb, ushort* __restrict__ vT){
  int idx = blockIdx.x*256 + threadIdx.x; // B*S*H*64
  int d2 = idx & 63, h = (idx>>6)&7, i = (idx>>9)&(S_-1), b = idx>>20;
  int row = b*S_ + i;
  float inv = __expf(-(float)d2 * 0.14391156831212787f);
  float ang = (float)i * inv;
  float sn, cs; sincosf(ang, &sn, &cs);
  const ushort* cr = C2 + (size_t)row*2048 + h*DH_ + d2;
  float x1 = bf2f(cr[0]), x2 = bf2f(cr[64]);
  size_t ko = ((size_t)(b*KV_ + i))*D_ + h*DH_ + d2;
  kb[ko] = f2bf(x1*cs - x2*sn); kb[ko+64] = f2bf(x1*sn + x2*cs);
  x1 = bf2f(cr[1024]); x2 = bf2f(cr[1088]);
  size_t vo = ((size_t)((b*H_ + h)*DH_ + d2))*KVP_ + i;
  vT[vo] = f2bf(x1); vT[vo + (size_t)64*KVP_] = f2bf(x2);
}

// ---------------- block-sparse flash attention ----------------
__global__ __launch_bounds__(256) void k_attn(const ushort* __restrict__ qb, const ushort* __restrict__ kb,
    const ushort* __restrict__ vT, const int* __restrict__ anch, ushort* __restrict__ ao){
  __shared__ float pbuf[4][16*36];
  const int lane = threadIdx.x & 63, w = threadIdx.x >> 6;
  const int l15 = lane & 15, g = lane >> 4;
  const int wi = blockIdx.x*4 + w;
  const int b = wi >> 10, qblk = (wi >> 3) & (NA_-1), h = wi & 7;
  const int anc = anch[b*NA_ + qblk];
  float* pb = pbuf[w];
  short8 aq[4];
  {
    const ushort* qr = qb + ((size_t)(b*Q_ + qblk*16 + l15))*D_ + h*DH_ + g*8;
    #pragma unroll
    for (int kc=0;kc<4;++kc) aq[kc] = *(const short8*)(qr + kc*32);
  }
  f32x4 o[8];
  #pragma unroll
  for (int cc=0;cc<8;++cc) o[cc] = f32x4{0.f,0.f,0.f,0.f};
  float m[4] = {-1e30f,-1e30f,-1e30f,-1e30f};
  float sl[4] = {0.f,0.f,0.f,0.f};
  const float SC = 0.08838834764831845f; // 1/sqrt(128)
  const ushort* vbase = vT + ((size_t)((b*H_ + h)*DH_))*KVP_;

  auto process = [&](int kv0, int limit){
    const bool have2 = (limit - kv0) > 16;
    f32x4 sc0 = {0.f,0.f,0.f,0.f}, sc1 = {0.f,0.f,0.f,0.f};
    const ushort* kr = kb + ((size_t)(b*KV_ + kv0 + l15))*D_ + h*DH_ + g*8;
    #pragma unroll
    for (int kc=0;kc<4;++kc){
      short8 bk = *(const short8*)(kr + kc*32);
      sc0 = mfma16(aq[kc], bk, sc0);
    }
    if (have2){
      const ushort* kr2 = kr + (size_t)16*D_;
      #pragma unroll
      for (int kc=0;kc<4;++kc){
        short8 bk = *(const short8*)(kr2 + kc*32);
        sc1 = mfma16(aq[kc], bk, sc1);
      }
    }
    int key0 = kv0 + l15, key1 = kv0 + 16 + l15;
    #pragma unroll
    for (int r=0;r<4;++r){
      float s0 = (key0 < limit) ? sc0[r]*SC : -1e30f;
      float s1 = (have2 && key1 < limit) ? sc1[r]*SC : -1e30f;
      float cm = rmax16(fmaxf(s0, s1));
      float mn = fmaxf(m[r], cm);
      float esc = __expf(m[r] - mn);
      float p0 = __expf(s0 - mn), p1 = __expf(s1 - mn);
      float rs = rsum16(p0 + p1);
      sl[r] = sl[r]*esc + rs;
      m[r] = mn;
      #pragma unroll
      for (int cc=0;cc<8;++cc) o[cc][r] *= esc;
      int q = g*4 + r;
      pb[q*36 + l15] = p0;
      pb[q*36 + 16 + l15] = p1;
    }
    asm volatile("s_waitcnt lgkmcnt(0)" ::: "memory");
    __builtin_amdgcn_sched_barrier(0);
    const float* pr = pb + l15*36 + g*8;
    float4 pa0 = *(const float4*)pr;
    float4 pa1 = *(const float4*)(pr + 4);
    short8 pa;
    pa[0]=(short)f2bf(pa0.x); pa[1]=(short)f2bf(pa0.y); pa[2]=(short)f2bf(pa0.z); pa[3]=(short)f2bf(pa0.w);
    pa[4]=(short)f2bf(pa1.x); pa[5]=(short)f2bf(pa1.y); pa[6]=(short)f2bf(pa1.z); pa[7]=(short)f2bf(pa1.w);
    const ushort* vr = vbase + kv0 + g*8;
    #pragma unroll
    for (int cc=0;cc<8;++cc){
      short8 bv = *(const short8*)(vr + (size_t)(cc*16 + l15)*KVP_);
      o[cc] = mfma16(pa, bv, o[cc]);
    }
  };
  for (int kv0 = 0; kv0 < anc; kv0 += 32) process(kv0, anc);
  {
    int kv0 = S_ + qblk*16;
    process(kv0, kv0 + 16);
  }
  #pragma unroll
  for (int cc=0;cc<8;++cc){
    #pragma unroll
    for (int r=0;r<4;++r){
      float val = o[cc][r] / sl[r];
      int q = g*4 + r;
      ao[((size_t)(b*Q_ + qblk*16 + q))*D_ + h*DH_ + cc*16 + l15] = f2bf(val);
    }
  }
}

// ---------------- residual + RMSNorm -> h bf16 ----------------
__global__ __launch_bounds__(256) void k_rms(const float* __restrict__ wo_out, const float* __restrict__ et,
    const int* __restrict__ draft, const float* __restrict__ nw, ushort* __restrict__ hb){
  const int row = blockIdx.x, tid = threadIdx.x;
  const int lane = tid & 63, w = tid >> 6;
  const float* wr = wo_out + (size_t)row*D_;
  const float* er = et + (size_t)draft[row]*D_;
  float v[4]; float ss = 0.f;
  #pragma unroll
  for (int j=0;j<4;++j){
    int d = tid + j*256;
    v[j] = er[d] + wr[d];
    ss += v[j]*v[j];
  }
  #pragma unroll
  for (int msk=1; msk<64; msk<<=1) ss += __shfl_xor(ss, msk);
  __shared__ float red[4];
  if (lane == 0) red[w] = ss;
  __syncthreads();
  float tot = red[0]+red[1]+red[2]+red[3];
  float rs = rsqrtf(tot*(1.f/1024.f) + 1e-6f);
  #pragma unroll
  for (int j=0;j<4;++j){
    int d = tid + j*256;
    hb[(size_t)row*D_ + d] = f2bf(v[j]*rs*nw[d]);
  }
}

// ---------------- combine NP_ slices -> per-block loss sums (deterministic) ----------------
__global__ __launch_bounds__(256) void k_combine(const float* __restrict__ pm, const float* __restrict__ pl,
    const float* __restrict__ pbv, const int* __restrict__ pbi, const float* __restrict__ plbl,
    const int* __restrict__ labels, float* __restrict__ pblk){
  const int row = blockIdx.x*256 + threadIdx.x;
  float M = -1e30f, Lx = 0.f;
  float bv = -1e30f; int bi = 0;
  for (int s=0;s<NP_;++s){
    size_t idx = (size_t)s*NROWS_ + row;
    float m = pm[idx], l = pl[idx];
    float Mn = fmaxf(M, m);
    Lx = Lx*__expf(M-Mn) + l*__expf(m-Mn);
    M = Mn;
    float v = pbv[idx];
    if (v > bv){ bv = v; bi = pbi[idx]; }
  }
  float logZ = M + logf(Lx);
  float lb = plbl[row];
  int lab = labels[row];
  bool valid = lab != -100;
  int p = row & 15;
  float wgt = (valid && p > 0) ? __expf(-(float)(p-1)*(1.f/7.f)) : 0.f;
  float nll = logZ - lb;
  float t0 = wgt*nll, t1 = wgt;
  float t2 = (valid && bi == lab) ? 1.f : 0.f, t3 = valid ? 1.f : 0.f;
  #pragma unroll
  for (int msk=1; msk<64; msk<<=1){
    t0 += __shfl_xor(t0, msk); t1 += __shfl_xor(t1, msk);
    t2 += __shfl_xor(t2, msk); t3 += __shfl_xor(t3, msk);
  }
  __shared__ float red[4][4];
  const int lane = threadIdx.x & 63, w = threadIdx.x >> 6;
  if (lane == 0){ red[w][0]=t0; red[w][1]=t1; red[w][2]=t2; red[w][3]=t3; }
  __syncthreads();
  if (threadIdx.x == 0){
    float s0=0,s1=0,s2=0,s3=0;
    for (int i=0;i<4;++i){ s0+=red[i][0]; s1+=red[i][1]; s2+=red[i][2]; s3+=red[i][3]; }
    pblk[blockIdx.x*4+0]=s0; pblk[blockIdx.x*4+1]=s1; pblk[blockIdx.x*4+2]=s2; pblk[blockIdx.x*4+3]=s3;
  }
}

__global__ void k_final(const float* __restrict__ pblk, float* __restrict__ out){
  if (threadIdx.x != 0 || blockIdx.x != 0) return;
  float s0=0,s1=0,s2=0,s3=0;
  for (int i=0;i<16;++i){ s0+=pblk[i*4]; s1+=pblk[i*4+1]; s2+=pblk[i*4+2]; s3+=pblk[i*4+3]; }
  out[0] = s0 / fmaxf(s1, 1e-6f);
  out[1] = s2 / fmaxf(s3, 1.f);
}

extern "C" void kernel_launch(void* const* d_in, const int* in_sizes, int n_in,
                              void* d_out, int out_size, void* d_ws, size_t ws_size,
                              hipStream_t stream){
  const int*   ids  = (const int*)d_in[0];
  const float* hs   = (const float*)d_in[1];
  const int*   anch = (const int*)d_in[2];
  const float* lmw  = (const float*)d_in[3];
  const float* nw   = (const float*)d_in[4];
  const float* fcw  = (const float*)d_in[5];
  const float* et   = (const float*)d_in[6];
  const float* wq   = (const float*)d_in[7];
  const float* wk   = (const float*)d_in[8];
  const float* wvp  = (const float*)d_in[9];
  const float* wo   = (const float*)d_in[10];
  float* out = (float*)d_out;
  (void)in_sizes; (void)n_in; (void)out_size; (void)ws_size;

  char* ws = (char*)d_ws;
  size_t off = 0;
  auto alloc = [&](size_t bytes)->char*{ char* p = ws + off; off = (off + bytes + 255) & ~(size_t)255; return p; };
  ushort* fcW   = (ushort*)alloc((size_t)1024*3072*2);
  ushort* Wqkv  = (ushort*)alloc((size_t)3072*1024*2);
  ushort* woW   = (ushort*)alloc((size_t)1024*1024*2);
  ushort* lmW   = (ushort*)alloc((size_t)V_*1024*2);
  ushort* ctx   = (ushort*)alloc((size_t)4096*1024*2);
  ushort* emb   = (ushort*)alloc((size_t)4096*1024*2);
  ushort* hcat  = (ushort*)alloc((size_t)4096*3072*2);   // reused as C1, then partial overlay
  ushort* C1 = hcat;
  ushort* C2    = (ushort*)alloc((size_t)4096*2048*2);   // reused as wo_out (f32)
  float* wo_out = (float*)C2;
  ushort* qbuf  = (ushort*)alloc((size_t)4096*1024*2);
  ushort* kbuf  = (ushort*)alloc((size_t)B_*KV_*1024*2);
  ushort* vT    = (ushort*)alloc((size_t)B_*H_*DH_*KVP_*2);
  ushort* ao    = (ushort*)alloc((size_t)4096*1024*2);
  ushort* hb    = (ushort*)alloc((size_t)4096*1024*2);
  int* draft  = (int*)alloc(4096*4);
  int* labels = (int*)alloc(4096*4);
  int* posf   = (int*)alloc(4096*4);
  float* plbl = (float*)alloc(4096*4);
  float* pblk = (float*)alloc(16*4*4);
  // partial arrays overlay dead-by-then buffers: ctx(8MB) emb(8MB) hcat(24MB) = 40MB
  // each partial array = NP_*NROWS_*4 = 8.192 MB
  float* pm  = (float*)ctx;
  float* pl  = (float*)emb;
  float* pbv = (float*)hcat;
  int*   pbi = (int*)(hcat + (size_t)NP_*NROWS_*2); // +8.192MB into hcat (ushort units: *2)

  k_meta<<<16,256,0,stream>>>(ids, anch, draft, labels, posf);
  k_hcat<<<6144,256,0,stream>>>(hs, hcat);
  k_cvt<<<1536,256,0,stream>>>(fcw, fcW, 1024*3072/8);
  k_cvt<<<512,256,0,stream>>>(wq, Wqkv, 1024*1024/8);
  k_cvt<<<512,256,0,stream>>>(wk, Wqkv + (size_t)1024*1024, 1024*1024/8);
  k_cvt<<<512,256,0,stream>>>(wvp, Wqkv + (size_t)2048*1024, 1024*1024/8);
  k_cvt<<<512,256,0,stream>>>(wo, woW, 1024*1024/8);
  k_cvt<<<16000,256,0,stream>>>(lmw, lmW, V_*1024/8);
  k_gather<<<2048,256,0,stream>>>(et, draft, emb);
  k_gemm<1><<<dim3(32,8),256,0,stream>>>(hcat, fcW, ctx, 1024, 3072);
  k_gemm<1><<<dim3(32,24),256,0,stream>>>(emb, Wqkv, C1, 3072, 1024);
  k_gemm<1><<<dim3(32,16),256,0,stream>>>(ctx, Wqkv + (size_t)1024*1024, C2, 2048, 1024);
  k_rope_draft<<<8192,256,0,stream>>>(C1, posf, qbuf, kbuf, vT);
  k_rope_ctx<<<8192,256,0,stream>>>(C2, kbuf, vT);
  k_attn<<<512,256,0,stream>>>(qbuf, kbuf, vT, anch, ao);
  k_gemm<0><<<dim3(32,8),256,0,stream>>>(ao, woW, wo_out, 1024, 1024);
  k_rms<<<4096,256,0,stream>>>(wo_out, et, draft, nw, hb);
  k_lbl<<<1024,256,0,stream>>>(hb, lmW, labels, plbl);
  k_lmgemm<<<dim3(32,250),256,0,stream>>>(hb, lmW, pm, pl, pbv, pbi);
  k_combine<<<16,256,0,stream>>>(pm, pl, pbv, pbi, plbl, labels, pblk);
  k_final<<<1,64,0,stream>>>(pblk, out);
}